// Round 2
// baseline (98.320 us; speedup 1.0000x reference)
//
#include <hip/hip_runtime.h>
#include <math.h>

#define TT 60
#define BB 64
#define STR 68
#define NBINS 45
#define TCH 4      // time chunks per block
#define TPER 15    // timesteps per chunk

// ---------------- Kernel 1: TKE (temporal variance) ----------------
// 2048 blocks x 256 threads; block = 64 float4-pixels x 4 time-chunks.
// Partial sums combined via LDS atomics (stride-17 pad: conflict-free).
__global__ __launch_bounds__(256, 6) void tke_kernel(const float* __restrict__ preds,
                                                     const float* __restrict__ trues,
                                                     float* __restrict__ tke) {
    __shared__ float red[64][17];   // [pixel][16 partials], padded stride

    int tid = threadIdx.x;
    int p   = tid & 63;     // pixel-lane within block
    int tc  = tid >> 6;     // time chunk 0..3

    int gid   = blockIdx.x;
    int input = gid >> 10;          // 1024 blocks per input
    int rem   = gid & 1023;
    int b     = rem >> 4;           // batch
    int pbase = (rem & 15) << 6;    // 16 blocks per image, 64 float4 each
    int p4    = pbase + p;

    const float4* src  = (const float4*)(input ? trues : preds);
    const float4* base = src + (size_t)b * (TT * 2048) + (size_t)(tc * TPER) * 2048 + p4;

    for (int i = tid; i < 64 * 17; i += 256) ((float*)red)[i] = 0.0f;
    __syncthreads();

    float su[4]  = {0,0,0,0}, squ[4] = {0,0,0,0};
    float sv[4]  = {0,0,0,0}, sqv[4] = {0,0,0,0};
    #pragma unroll 3
    for (int t = 0; t < TPER; ++t) {
        float4 u = base[t * 2048];          // c = 0
        float4 v = base[t * 2048 + 1024];   // c = 1
        float uu[4] = {u.x, u.y, u.z, u.w};
        float vv[4] = {v.x, v.y, v.z, v.w};
        #pragma unroll
        for (int j = 0; j < 4; ++j) {
            su[j]  += uu[j];  squ[j] += uu[j] * uu[j];
            sv[j]  += vv[j];  sqv[j] += vv[j] * vv[j];
        }
    }

    #pragma unroll
    for (int j = 0; j < 4; ++j) {
        atomicAdd(&red[p][j],      su[j]);
        atomicAdd(&red[p][4 + j],  squ[j]);
        atomicAdd(&red[p][8 + j],  sv[j]);
        atomicAdd(&red[p][12 + j], sqv[j]);
    }
    __syncthreads();

    if (tc == 0) {
        const float inv = 1.0f / 60.0f;
        float o[4];
        #pragma unroll
        for (int j = 0; j < 4; ++j) {
            float mu = red[p][j] * inv;
            float mv = red[p][8 + j] * inv;
            o[j] = 0.5f * ((red[p][4 + j] * inv - mu * mu) +
                           (red[p][12 + j] * inv - mv * mv));
        }
        float4 outv; outv.x = o[0]; outv.y = o[1]; outv.z = o[2]; outv.w = o[3];
        ((float4*)tke)[(size_t)(input * BB + b) * 1024 + p4] = outv;
    }
}

// ---------------- Kernel 2: 2D DFT + power + radial bin sums ----------------
// one block (512 threads) per image; 128 images (64 preds then 64 trues)
__global__ __launch_bounds__(512) void dft_kernel(const float* __restrict__ tke,
                                                  float* __restrict__ binsums) {
    __shared__ __align__(16) float tke_s[64 * 64];
    __shared__ __align__(16) float Gr[64 * STR];   // stored [x][k], stride 68
    __shared__ __align__(16) float Gi[64 * STR];
    __shared__ float ctab[64], stab[64];
    __shared__ float bins_s[NBINS];

    int tid = threadIdx.x;
    int img = blockIdx.x;

    if (tid < 64) {
        float ang = (float)tid * 0.09817477042468103871f;   // 2*pi/64
        float ss, cc;
        sincosf(ang, &ss, &cc);
        ctab[tid] = cc; stab[tid] = ss;
    }
    if (tid < NBINS) bins_s[tid] = 0.0f;

    // load TKE image to LDS
    {
        const float4* src = (const float4*)(tke + (size_t)img * 4096);
        float4* dst = (float4*)tke_s;
        for (int i = tid; i < 1024; i += 512) dst[i] = src[i];
    }
    __syncthreads();

    // Stage A: G[k][x] = sum_y tke[y][x] * exp(-2pi i k y / 64)
    // thread owns k = tid>>3 (0..63), x-range x0..x0+7
    {
        int k  = tid >> 3;
        int x0 = (tid & 7) * 8;
        float gr[8] = {0,0,0,0,0,0,0,0};
        float gi[8] = {0,0,0,0,0,0,0,0};
        for (int y = 0; y < 64; ++y) {
            float4 ta = *(const float4*)&tke_s[(y << 6) + x0];
            float4 tb = *(const float4*)&tke_s[(y << 6) + x0 + 4];
            float tv[8] = {ta.x, ta.y, ta.z, ta.w, tb.x, tb.y, tb.z, tb.w};
            int idx = (k * y) & 63;
            float cc = ctab[idx], ss = stab[idx];
            #pragma unroll
            for (int j = 0; j < 8; ++j) {
                gr[j] += cc * tv[j];
                gi[j] -= ss * tv[j];
            }
        }
        #pragma unroll
        for (int j = 0; j < 8; ++j) {           // transposed store: G[x][k]
            Gr[(x0 + j) * STR + k] = gr[j];
            Gi[(x0 + j) * STR + k] = gi[j];
        }
    }
    __syncthreads();

    // Stage B: F[k][l] = sum_x G[k][x] * exp(-2pi i l x / 64); power + binning
    // thread owns l = tid>>3 (0..63), k-range k0..k0+7
    {
        int l  = tid >> 3;
        int k0 = (tid & 7) * 8;
        float fr[8] = {0,0,0,0,0,0,0,0};
        float fi[8] = {0,0,0,0,0,0,0,0};
        for (int x = 0; x < 64; ++x) {
            float4 a0 = *(const float4*)&Gr[x * STR + k0];
            float4 a1 = *(const float4*)&Gr[x * STR + k0 + 4];
            float4 b0 = *(const float4*)&Gi[x * STR + k0];
            float4 b1 = *(const float4*)&Gi[x * STR + k0 + 4];
            float ar[8] = {a0.x, a0.y, a0.z, a0.w, a1.x, a1.y, a1.z, a1.w};
            float br[8] = {b0.x, b0.y, b0.z, b0.w, b1.x, b1.y, b1.z, b1.w};
            int idx = (l * x) & 63;
            float cc = ctab[idx], ss = stab[idx];
            #pragma unroll
            for (int j = 0; j < 8; ++j) {
                fr[j] += ar[j] * cc + br[j] * ss;
                fi[j] += br[j] * cc - ar[j] * ss;
            }
        }
        float fl = (float)((l + 32) & 63) - 31.5f;
        #pragma unroll
        for (int j = 0; j < 8; ++j) {
            int k = k0 + j;
            float fk = (float)((k + 32) & 63) - 31.5f;
            float r = sqrtf(fk * fk + fl * fl);
            int bin = (int)r;
            float pw = fr[j] * fr[j] + fi[j] * fi[j];
            atomicAdd(&bins_s[bin], pw);
        }
    }
    __syncthreads();
    if (tid < NBINS) binsums[img * NBINS + tid] = bins_s[tid];
}

// ---------------- Kernel 3: MSE over azimuthal spectra ----------------
__global__ __launch_bounds__(256) void loss_kernel(const float* __restrict__ binsums,
                                                   float* __restrict__ out) {
    __shared__ int   cnt[NBINS];
    __shared__ float part[256];
    int tid = threadIdx.x;
    if (tid < NBINS) cnt[tid] = 0;
    __syncthreads();
    for (int p = tid; p < 4096; p += 256) {
        float dy = (float)(p >> 6) - 31.5f;
        float dx = (float)(p & 63) - 31.5f;
        int bin = (int)sqrtf(dy * dy + dx * dx);
        atomicAdd(&cnt[bin], 1);
    }
    __syncthreads();
    float acc = 0.0f;
    for (int j = tid; j < BB * 43; j += 256) {
        int b   = j / 43;
        int bin = j - b * 43 + 1;           // returned bins are 1..43
        float n  = (float)cnt[bin];
        float st = binsums[(BB + b) * NBINS + bin] / n;   // trues
        float sp = binsums[b * NBINS + bin] / n;          // preds
        float d  = st - sp;
        acc += d * d;
    }
    part[tid] = acc;
    __syncthreads();
    for (int s = 128; s > 0; s >>= 1) {
        if (tid < s) part[tid] += part[tid + s];
        __syncthreads();
    }
    if (tid == 0) out[0] = part[0] * (1.0f / (BB * 43.0f));
}

extern "C" void kernel_launch(void* const* d_in, const int* in_sizes, int n_in,
                              void* d_out, int out_size, void* d_ws, size_t ws_size,
                              hipStream_t stream) {
    const float* preds = (const float*)d_in[0];
    const float* trues = (const float*)d_in[1];
    float* tke     = (float*)d_ws;                  // 2*64*4096 floats = 2 MB
    float* binsums = tke + 2 * BB * 4096;           // 128*45 floats

    tke_kernel<<<2048, 256, 0, stream>>>(preds, trues, tke);
    dft_kernel<<<128, 512, 0, stream>>>(tke, binsums);
    loss_kernel<<<1, 256, 0, stream>>>(binsums, (float*)d_out);
}

// Round 3
// 69.831 us; speedup vs baseline: 1.4080x; 1.4080x over previous
//
#include <hip/hip_runtime.h>
#include <math.h>

#define TT 60
#define BB 64
#define STR 68
#define NBINS 45

// ---------------- Kernel 1: TKE (temporal variance) ----------------
// 1024 blocks x 256 threads. Block = 128 float4-pixels x 2 time-halves (30 t each).
// Reduction: upper half writes partials to stride-17 LDS (conflict-free),
// one sync, lower half combines and finalizes. Deep unroll for MLP.
__global__ __launch_bounds__(256, 4) void tke_kernel(const float* __restrict__ preds,
                                                     const float* __restrict__ trues,
                                                     float* __restrict__ tke) {
    __shared__ float red[128][17];   // [pixel][16 partials], padded stride

    int tid = threadIdx.x;
    int p   = tid & 127;    // pixel within block's 128-float4 group
    int th  = tid >> 7;     // time half 0/1

    int bid    = blockIdx.x;
    int input  = bid >> 9;          // 512 blocks per input
    int rem    = bid & 511;
    int b      = rem >> 3;          // batch
    int pgroup = rem & 7;           // 8 blocks per image, 128 float4 each
    int p4     = pgroup * 128 + p;

    const float4* src  = (const float4*)(input ? trues : preds);
    const float4* base = src + (size_t)b * (TT * 2048) + (size_t)(th * 30) * 2048 + p4;

    float su[4]  = {0,0,0,0}, squ[4] = {0,0,0,0};
    float sv[4]  = {0,0,0,0}, sqv[4] = {0,0,0,0};
    #pragma unroll 5
    for (int t = 0; t < 30; ++t) {
        float4 u = base[t * 2048];          // c = 0
        float4 v = base[t * 2048 + 1024];   // c = 1
        float uu[4] = {u.x, u.y, u.z, u.w};
        float vv[4] = {v.x, v.y, v.z, v.w};
        #pragma unroll
        for (int j = 0; j < 4; ++j) {
            su[j]  += uu[j];  squ[j] += uu[j] * uu[j];
            sv[j]  += vv[j];  sqv[j] += vv[j] * vv[j];
        }
    }

    if (th == 1) {
        #pragma unroll
        for (int j = 0; j < 4; ++j) {
            red[p][j]      = su[j];
            red[p][4 + j]  = squ[j];
            red[p][8 + j]  = sv[j];
            red[p][12 + j] = sqv[j];
        }
    }
    __syncthreads();

    if (th == 0) {
        const float inv = 1.0f / 60.0f;
        float o[4];
        #pragma unroll
        for (int j = 0; j < 4; ++j) {
            float tsu  = su[j]  + red[p][j];
            float tsqu = squ[j] + red[p][4 + j];
            float tsv  = sv[j]  + red[p][8 + j];
            float tsqv = sqv[j] + red[p][12 + j];
            float mu = tsu * inv, mv = tsv * inv;
            o[j] = 0.5f * ((tsqu * inv - mu * mu) + (tsqv * inv - mv * mv));
        }
        float4 outv; outv.x = o[0]; outv.y = o[1]; outv.z = o[2]; outv.w = o[3];
        ((float4*)tke)[(size_t)(input * BB + b) * 1024 + p4] = outv;
    }
}

// ---------------- Kernel 2: 2D DFT + power + radial bin sums ----------------
// one block (512 threads) per image; 128 images (64 preds then 64 trues)
__global__ __launch_bounds__(512) void dft_kernel(const float* __restrict__ tke,
                                                  float* __restrict__ binsums) {
    __shared__ __align__(16) float tke_s[64 * 64];
    __shared__ __align__(16) float Gr[64 * STR];   // stored [x][k], stride 68
    __shared__ __align__(16) float Gi[64 * STR];
    __shared__ float ctab[64], stab[64];
    __shared__ float bins_s[NBINS];

    int tid = threadIdx.x;
    int img = blockIdx.x;

    if (tid < 64) {
        float ang = (float)tid * 0.09817477042468103871f;   // 2*pi/64
        float ss, cc;
        sincosf(ang, &ss, &cc);
        ctab[tid] = cc; stab[tid] = ss;
    }
    if (tid < NBINS) bins_s[tid] = 0.0f;

    // load TKE image to LDS
    {
        const float4* src = (const float4*)(tke + (size_t)img * 4096);
        float4* dst = (float4*)tke_s;
        for (int i = tid; i < 1024; i += 512) dst[i] = src[i];
    }
    __syncthreads();

    // Stage A: G[k][x] = sum_y tke[y][x] * exp(-2pi i k y / 64)
    // thread owns k = tid>>3 (0..63), x-range x0..x0+7
    {
        int k  = tid >> 3;
        int x0 = (tid & 7) * 8;
        float gr[8] = {0,0,0,0,0,0,0,0};
        float gi[8] = {0,0,0,0,0,0,0,0};
        for (int y = 0; y < 64; ++y) {
            float4 ta = *(const float4*)&tke_s[(y << 6) + x0];
            float4 tb = *(const float4*)&tke_s[(y << 6) + x0 + 4];
            float tv[8] = {ta.x, ta.y, ta.z, ta.w, tb.x, tb.y, tb.z, tb.w};
            int idx = (k * y) & 63;
            float cc = ctab[idx], ss = stab[idx];
            #pragma unroll
            for (int j = 0; j < 8; ++j) {
                gr[j] += cc * tv[j];
                gi[j] -= ss * tv[j];
            }
        }
        #pragma unroll
        for (int j = 0; j < 8; ++j) {           // transposed store: G[x][k]
            Gr[(x0 + j) * STR + k] = gr[j];
            Gi[(x0 + j) * STR + k] = gi[j];
        }
    }
    __syncthreads();

    // Stage B: F[k][l] = sum_x G[k][x] * exp(-2pi i l x / 64); power + binning
    // thread owns l = tid>>3 (0..63), k-range k0..k0+7
    {
        int l  = tid >> 3;
        int k0 = (tid & 7) * 8;
        float fr[8] = {0,0,0,0,0,0,0,0};
        float fi[8] = {0,0,0,0,0,0,0,0};
        for (int x = 0; x < 64; ++x) {
            float4 a0 = *(const float4*)&Gr[x * STR + k0];
            float4 a1 = *(const float4*)&Gr[x * STR + k0 + 4];
            float4 b0 = *(const float4*)&Gi[x * STR + k0];
            float4 b1 = *(const float4*)&Gi[x * STR + k0 + 4];
            float ar[8] = {a0.x, a0.y, a0.z, a0.w, a1.x, a1.y, a1.z, a1.w};
            float br[8] = {b0.x, b0.y, b0.z, b0.w, b1.x, b1.y, b1.z, b1.w};
            int idx = (l * x) & 63;
            float cc = ctab[idx], ss = stab[idx];
            #pragma unroll
            for (int j = 0; j < 8; ++j) {
                fr[j] += ar[j] * cc + br[j] * ss;
                fi[j] += br[j] * cc - ar[j] * ss;
            }
        }
        float fl = (float)((l + 32) & 63) - 31.5f;
        #pragma unroll
        for (int j = 0; j < 8; ++j) {
            int k = k0 + j;
            float fk = (float)((k + 32) & 63) - 31.5f;
            float r = sqrtf(fk * fk + fl * fl);
            int bin = (int)r;
            float pw = fr[j] * fr[j] + fi[j] * fi[j];
            atomicAdd(&bins_s[bin], pw);
        }
    }
    __syncthreads();
    if (tid < NBINS) binsums[img * NBINS + tid] = bins_s[tid];
}

// ---------------- Kernel 3: MSE over azimuthal spectra ----------------
__global__ __launch_bounds__(256) void loss_kernel(const float* __restrict__ binsums,
                                                   float* __restrict__ out) {
    __shared__ int   cnt[NBINS];
    __shared__ float part[256];
    int tid = threadIdx.x;
    if (tid < NBINS) cnt[tid] = 0;
    __syncthreads();
    for (int p = tid; p < 4096; p += 256) {
        float dy = (float)(p >> 6) - 31.5f;
        float dx = (float)(p & 63) - 31.5f;
        int bin = (int)sqrtf(dy * dy + dx * dx);
        atomicAdd(&cnt[bin], 1);
    }
    __syncthreads();
    float acc = 0.0f;
    for (int j = tid; j < BB * 43; j += 256) {
        int b   = j / 43;
        int bin = j - b * 43 + 1;           // returned bins are 1..43
        float n  = (float)cnt[bin];
        float st = binsums[(BB + b) * NBINS + bin] / n;   // trues
        float sp = binsums[b * NBINS + bin] / n;          // preds
        float d  = st - sp;
        acc += d * d;
    }
    part[tid] = acc;
    __syncthreads();
    for (int s = 128; s > 0; s >>= 1) {
        if (tid < s) part[tid] += part[tid + s];
        __syncthreads();
    }
    if (tid == 0) out[0] = part[0] * (1.0f / (BB * 43.0f));
}

extern "C" void kernel_launch(void* const* d_in, const int* in_sizes, int n_in,
                              void* d_out, int out_size, void* d_ws, size_t ws_size,
                              hipStream_t stream) {
    const float* preds = (const float*)d_in[0];
    const float* trues = (const float*)d_in[1];
    float* tke     = (float*)d_ws;                  // 2*64*4096 floats = 2 MB
    float* binsums = tke + 2 * BB * 4096;           // 128*45 floats

    tke_kernel<<<1024, 256, 0, stream>>>(preds, trues, tke);
    dft_kernel<<<128, 512, 0, stream>>>(tke, binsums);
    loss_kernel<<<1, 256, 0, stream>>>(binsums, (float*)d_out);
}